// Round 5
// baseline (638.724 us; speedup 1.0000x reference)
//
#include <hip/hip_runtime.h>
#include <cstdint>
#include <cstddef>

#define NB 16384
#define NA 8
#define NE 512
#define NK 1024   // 2E
#define NN 4096   // A*E

typedef __bf16 bf16x8 __attribute__((ext_vector_type(8)));
typedef float  f32x4  __attribute__((ext_vector_type(4)));
typedef uint16_t u16x8 __attribute__((ext_vector_type(8)));

__device__ __forceinline__ uint16_t cvt_bf16(float f) {
    uint32_t u = __builtin_bit_cast(uint32_t, f);
    u += 0x7fffu + ((u >> 16) & 1u);
    return (uint16_t)(u >> 16);
}

// old BK=32 chunk swizzle (k_prep + fallback kernels)
__device__ __forceinline__ int swz(int row) { return (row ^ (row >> 2)) & 3; }

__device__ __forceinline__ void gl_lds16(const void* g, void* l) {
    __builtin_amdgcn_global_load_lds(
        (__attribute__((address_space(1))) void*)(void*)g,
        (__attribute__((address_space(3))) void*)l, 16, 0, 0);
}

__device__ __forceinline__ void waitv4() { asm volatile("s_waitcnt vmcnt(4)" ::: "memory"); }
__device__ __forceinline__ void waitv0() { asm volatile("s_waitcnt vmcnt(0)" ::: "memory"); }
__device__ __forceinline__ void barx()  { asm volatile("s_barrier" ::: "memory"); }

// conflict-free BK=32 tile position (16B units): row-pair interleave + 3-bit XOR
__device__ __forceinline__ int cf_pos(int row, int c) {
    return ((row >> 1) << 3) + ((((row & 1) << 2) + c) ^ ((row >> 1) & 7));
}

// f32 [nmat][R][C] -> bf16 [nmat][C][R]
__global__ __launch_bounds__(256) void k_tcvt(const float* __restrict__ in,
                                              uint16_t* __restrict__ out,
                                              int R, int C) {
    __shared__ float tile[32][33];
    int mat = blockIdx.z;
    int c0 = blockIdx.x * 32, r0 = blockIdx.y * 32;
    int tx = threadIdx.x & 31, ty = threadIdx.x >> 5;
    const float* src = in + (size_t)mat * R * C;
    uint16_t* dst = out + (size_t)mat * R * C;
#pragma unroll
    for (int yy = 0; yy < 4; ++yy) {
        int r = ty + yy * 8;
        tile[r][tx] = src[(size_t)(r0 + r) * C + c0 + tx];
    }
    __syncthreads();
#pragma unroll
    for (int yy = 0; yy < 4; ++yy) {
        int c = ty + yy * 8;
        dst[(size_t)(c0 + c) * R + r0 + tx] = cvt_bf16(tile[tx][c]);
    }
}

// f32 -> bf16 flat, 4 elems/thread
__global__ __launch_bounds__(256) void k_cvt4(const float* __restrict__ in,
                                              uint16_t* __restrict__ out, int n4) {
    int i = blockIdx.x * 256 + threadIdx.x;
    if (i >= n4) return;
    float4 v = ((const float4*)in)[i];
    ushort4 o;
    o.x = cvt_bf16(v.x); o.y = cvt_bf16(v.y); o.z = cvt_bf16(v.z); o.w = cvt_bf16(v.w);
    ((ushort4*)out)[i] = o;
}

// bvec[a*E+j] += partial over 32 i's; 128 blocks, atomics (bvec pre-zeroed)
__global__ __launch_bounds__(256) void k_bvec(const float* __restrict__ lb,
                                              const float* __restrict__ fwd,
                                              float* __restrict__ bvec) {
    int a = blockIdx.x >> 4, i0 = (blockIdx.x & 15) * 32;
    int t = threadIdx.x;
    float s0 = 0.f, s1 = 0.f;
#pragma unroll 4
    for (int i = 0; i < 32; ++i) {
        float w = lb[i0 + i];
        const float* f = fwd + ((size_t)a * NE + i0 + i) * NE;
        s0 = fmaf(w, f[t], s0);
        s1 = fmaf(w, f[t + 256], s1);
    }
    atomicAdd(&bvec[a * NE + t], s0);
    atomicAdd(&bvec[a * NE + t + 256], s1);
}

// TM[m=k'(1024)][n=(a,j)(4096)] = sum_i lwT[m][i]*fwdT[n][i]; store TMT[n][m] bf16
__global__ __launch_bounds__(256) void k_prep(const uint16_t* __restrict__ lwT,
                                              const uint16_t* __restrict__ fwdT,
                                              uint16_t* __restrict__ TMT) {
    __shared__ alignas(16) uint16_t lA[128 * 32];
    __shared__ alignas(16) uint16_t lB[128 * 32];
    int bz = blockIdx.x;
    int nt = bz & 31, mt = bz >> 5;
    int m0 = mt * 128, n0 = nt * 128;
    int t = threadIdx.x, lane = t & 63;
    int w = t >> 6, wm = w >> 1, wn = w & 1;
    int lr = lane & 15, lc = lane >> 4;
    int sl = swz(lr);
    f32x4 acc[4][4] = {};
    for (int k0 = 0; k0 < NE; k0 += 32) {
        __syncthreads();
#pragma unroll
        for (int p = 0; p < 2; ++p) {
            int idx = p * 256 + t;
            int row = idx >> 2, c16 = (idx & 3) ^ swz(row);
            gl_lds16(lwT + (size_t)(m0 + row) * NE + k0 + c16 * 8, lA + idx * 8);
            gl_lds16(fwdT + (size_t)(n0 + row) * NE + k0 + c16 * 8, lB + idx * 8);
        }
        __syncthreads();
        bf16x8 af[4], bfr[4];
#pragma unroll
        for (int i = 0; i < 4; ++i)
            af[i] = *(const bf16x8*)&lA[(wm * 64 + i * 16 + lr) * 32 + ((lc ^ sl) << 3)];
#pragma unroll
        for (int j = 0; j < 4; ++j)
            bfr[j] = *(const bf16x8*)&lB[(wn * 64 + j * 16 + lr) * 32 + ((lc ^ sl) << 3)];
#pragma unroll
        for (int i = 0; i < 4; ++i)
#pragma unroll
            for (int j = 0; j < 4; ++j)
                acc[i][j] = __builtin_amdgcn_mfma_f32_16x16x32_bf16(af[i], bfr[j], acc[i][j], 0, 0, 0);
    }
#pragma unroll
    for (int i = 0; i < 4; ++i) {
        int mb = m0 + wm * 64 + i * 16 + lc * 4;
#pragma unroll
        for (int j = 0; j < 4; ++j) {
            int n = n0 + wn * 64 + j * 16 + lr;
            ushort4 v;
            v.x = cvt_bf16(acc[i][j][0]);
            v.y = cvt_bf16(acc[i][j][1]);
            v.z = cvt_bf16(acc[i][j][2]);
            v.w = cvt_bf16(acc[i][j][3]);
            *(ushort4*)&TMT[(size_t)n * NK + mb] = v;
        }
    }
}

// ===== fast path: counted-vmcnt 2-phase dbuf, conflict-free layout =====

// attr[b,a,j] = img[b]@TM_a[0:512] + edge[b,a]@TM_a[512:1024] + bvec_a[j]
__global__ __launch_bounds__(256) void k_mm2(const uint16_t* __restrict__ imgb,
                                             const uint16_t* __restrict__ edgeb,
                                             const uint16_t* __restrict__ TMT,
                                             const float* __restrict__ bvec,
                                             float* __restrict__ attr,
                                             uint16_t* __restrict__ attrb) {
    __shared__ alignas(16) uint16_t lA[2][128 * 32];
    __shared__ alignas(16) uint16_t lB[2][128 * 32];
    int o = blockIdx.x;            // 4096 = 8 xcd * 512
    int a = o & 7, idx = o >> 3;
    int jt = idx & 3, mt = idx >> 2;
    int m0 = mt * 128, jb = jt * 128;
    int t = threadIdx.x, lane = t & 63;
    int w = t >> 6, wm = w >> 1, wn = w & 1;
    int lr = lane & 15, lc = lane >> 4;
    // stage source map (inverse of cf_pos): LDS unit u -> (row, c8)
    int srow[2], sc8[2];
#pragma unroll
    for (int p = 0; p < 2; ++p) {
        int u = p * 256 + t;
        int rp = u >> 3, q = (u & 7) ^ (rp & 7);
        srow[p] = (rp << 1) | (q >> 2);
        sc8[p] = (q & 3) << 3;
    }
    // frag read offsets (elem idx), constant across K-steps
    int aoff[4], boff[4];
#pragma unroll
    for (int i = 0; i < 4; ++i) {
        aoff[i] = cf_pos(wm * 64 + i * 16 + lr, lc) * 8;
        boff[i] = cf_pos(wn * 64 + i * 16 + lr, lc) * 8;
    }
    auto stage = [&](int buf, int s) {
        int k0 = s * 32;
#pragma unroll
        for (int p = 0; p < 2; ++p) {
            int u = p * 256 + t;
            const uint16_t* asrc = (k0 < NE)
                ? imgb + (size_t)(m0 + srow[p]) * NE + k0 + sc8[p]
                : edgeb + ((size_t)(m0 + srow[p]) * NA + a) * NE + (k0 - NE) + sc8[p];
            gl_lds16(asrc, &lA[buf][u * 8]);
            gl_lds16(TMT + (size_t)(a * NE + jb + srow[p]) * NK + k0 + sc8[p],
                     &lB[buf][u * 8]);
        }
    };
    f32x4 acc[4][4] = {};
    stage(0, 0);
    for (int s = 0; s < 32; ++s) {
        int cur = s & 1;
        if (s < 31) { stage(cur ^ 1, s + 1); waitv4(); } else { waitv0(); }
        barx();
        bf16x8 af[4], bfr[4];
#pragma unroll
        for (int i = 0; i < 4; ++i) af[i] = *(const bf16x8*)&lA[cur][aoff[i]];
#pragma unroll
        for (int j = 0; j < 4; ++j) bfr[j] = *(const bf16x8*)&lB[cur][boff[j]];
#pragma unroll
        for (int i = 0; i < 4; ++i)
#pragma unroll
            for (int j = 0; j < 4; ++j)
                acc[i][j] = __builtin_amdgcn_mfma_f32_16x16x32_bf16(af[i], bfr[j], acc[i][j], 0, 0, 0);
        barx();
    }
#pragma unroll
    for (int j = 0; j < 4; ++j) {
        float bv = bvec[a * NE + jb + wn * 64 + j * 16 + lr];
#pragma unroll
        for (int i = 0; i < 4; ++i)
#pragma unroll
            for (int r = 0; r < 4; ++r)
                acc[i][j][r] += bv;
    }
#pragma unroll
    for (int i = 0; i < 4; ++i) {
#pragma unroll
        for (int r = 0; r < 4; ++r) {
            int bm = m0 + wm * 64 + i * 16 + lc * 4 + r;
            float* orow = attr + ((size_t)bm * NA + a) * NE + jb;
            uint16_t* brow = attrb + ((size_t)bm * NA + a) * NE + jb;
#pragma unroll
            for (int j = 0; j < 4; ++j) {
                orow[wn * 64 + j * 16 + lr] = acc[i][j][r];
                brow[wn * 64 + j * 16 + lr] = cvt_bf16(acc[i][j][r]);
            }
        }
    }
}

// ind[b,j] += sum_{a in half} sw[a]*relu(attrb[b,a,:]@bwd_a[:,j]); counted schedule
__global__ __launch_bounds__(256) void k_ind3(const uint16_t* __restrict__ attrb,
                                              const uint16_t* __restrict__ bwdT,
                                              const float* __restrict__ sw,
                                              float* __restrict__ ind) {
    __shared__ alignas(16) uint16_t lA[2][128 * 32];
    __shared__ alignas(16) uint16_t lB[2][128 * 32];
    int o = blockIdx.x;            // 1024 = 8 xcd * 128
    int xcd = o & 7, mt = o >> 3;
    int jt = xcd >> 1, ah = xcd & 1;
    int m0 = mt * 128, jb = jt * 128, a0 = ah * 4;
    int t = threadIdx.x, lane = t & 63;
    int w = t >> 6, wm = w >> 1, wn = w & 1;
    int lr = lane & 15, lc = lane >> 4;
    int srow[2], sc8[2];
#pragma unroll
    for (int p = 0; p < 2; ++p) {
        int u = p * 256 + t;
        int rp = u >> 3, q = (u & 7) ^ (rp & 7);
        srow[p] = (rp << 1) | (q >> 2);
        sc8[p] = (q & 3) << 3;
    }
    int aoff[4], boff[4];
#pragma unroll
    for (int i = 0; i < 4; ++i) {
        aoff[i] = cf_pos(wm * 64 + i * 16 + lr, lc) * 8;
        boff[i] = cf_pos(wn * 64 + i * 16 + lr, lc) * 8;
    }
    float wav[4];
#pragma unroll
    for (int q = 0; q < 4; ++q) wav[q] = sw[a0 + q];
    waitv0();  // drain sw loads so in-loop vmcnt counting is exact
    auto stage = [&](int buf, int s) {
        int a = a0 + (s >> 4), kk = (s & 15) * 32;
#pragma unroll
        for (int p = 0; p < 2; ++p) {
            int u = p * 256 + t;
            gl_lds16(attrb + ((size_t)(m0 + srow[p]) * NA + a) * NE + kk + sc8[p],
                     &lA[buf][u * 8]);
            gl_lds16(bwdT + (size_t)(a * NE + jb + srow[p]) * NE + kk + sc8[p],
                     &lB[buf][u * 8]);
        }
    };
    f32x4 res[4][4] = {};
    stage(0, 0);
#pragma unroll
    for (int aa = 0; aa < 4; ++aa) {
        f32x4 acc[4][4] = {};
        for (int ss = 0; ss < 16; ++ss) {
            int s = aa * 16 + ss;
            int cur = s & 1;
            if (s < 63) { stage(cur ^ 1, s + 1); waitv4(); } else { waitv0(); }
            barx();
            bf16x8 af[4], bfr[4];
#pragma unroll
            for (int i = 0; i < 4; ++i) af[i] = *(const bf16x8*)&lA[cur][aoff[i]];
#pragma unroll
            for (int j = 0; j < 4; ++j) bfr[j] = *(const bf16x8*)&lB[cur][boff[j]];
#pragma unroll
            for (int i = 0; i < 4; ++i)
#pragma unroll
                for (int j = 0; j < 4; ++j)
                    acc[i][j] = __builtin_amdgcn_mfma_f32_16x16x32_bf16(af[i], bfr[j], acc[i][j], 0, 0, 0);
            barx();
        }
        float wa = wav[aa];
#pragma unroll
        for (int i = 0; i < 4; ++i)
#pragma unroll
            for (int j = 0; j < 4; ++j)
#pragma unroll
                for (int r = 0; r < 4; ++r)
                    res[i][j][r] += wa * fmaxf(acc[i][j][r], 0.f);
    }
#pragma unroll
    for (int i = 0; i < 4; ++i) {
#pragma unroll
        for (int r = 0; r < 4; ++r) {
            int bm = m0 + wm * 64 + i * 16 + lc * 4 + r;
            float* orow = ind + (size_t)bm * NE + jb;
#pragma unroll
            for (int j = 0; j < 4; ++j)
                atomicAdd(&orow[wn * 64 + j * 16 + lr], res[i][j][r]);
        }
    }
}

// ===== fallback path (R4 generic, __syncthreads-based) =====

template<bool EDGEB, bool WB>
__global__ __launch_bounds__(256) void k_mm(const uint16_t* __restrict__ imgb,
                                            const float* __restrict__ edgef,
                                            const uint16_t* __restrict__ edgeb,
                                            const uint16_t* __restrict__ TMT,
                                            const float* __restrict__ bvec,
                                            float* __restrict__ attr,
                                            uint16_t* __restrict__ attrb) {
    __shared__ alignas(16) uint16_t lA[2][128 * 32];
    __shared__ alignas(16) uint16_t lB[2][128 * 32];
    int o = blockIdx.x;
    int xcd = o & 7, idx = o >> 3;
    int a = xcd, jt = idx & 3, mt = idx >> 2;
    int m0 = mt * 128, jb = jt * 128;
    int t = threadIdx.x, lane = t & 63;
    int w = t >> 6, wm = w >> 1, wn = w & 1;
    int lr = lane & 15, lc = lane >> 4;
    int sl = swz(lr);
    int srow[2], scol[2];
#pragma unroll
    for (int p = 0; p < 2; ++p) {
        int id = p * 256 + t;
        srow[p] = id >> 2;
        scol[p] = ((id & 3) ^ swz(id >> 2)) << 3;
    }
    f32x4 acc[4][4];
#pragma unroll
    for (int j = 0; j < 4; ++j) {
        float bv = bvec[a * NE + jb + wn * 64 + j * 16 + lr];
        f32x4 b4 = {bv, bv, bv, bv};
#pragma unroll
        for (int i = 0; i < 4; ++i) acc[i][j] = b4;
    }
    auto stage = [&](int buf, int s) {
        int k0 = s * 32;
        if (k0 < NE) {
#pragma unroll
            for (int p = 0; p < 2; ++p)
                gl_lds16(imgb + (size_t)(m0 + srow[p]) * NE + k0 + scol[p],
                         &lA[buf][(p * 256 + t) * 8]);
        } else if (EDGEB) {
#pragma unroll
            for (int p = 0; p < 2; ++p)
                gl_lds16(edgeb + ((size_t)(m0 + srow[p]) * NA + a) * NE + (k0 - NE) + scol[p],
                         &lA[buf][(p * 256 + t) * 8]);
        } else {
#pragma unroll
            for (int p = 0; p < 2; ++p) {
                const float* sp = edgef + ((size_t)(m0 + srow[p]) * NA + a) * NE + (k0 - NE) + scol[p];
                float4 v0 = ((const float4*)sp)[0];
                float4 v1 = ((const float4*)sp)[1];
                u16x8 ov = {cvt_bf16(v0.x), cvt_bf16(v0.y), cvt_bf16(v0.z), cvt_bf16(v0.w),
                            cvt_bf16(v1.x), cvt_bf16(v1.y), cvt_bf16(v1.z), cvt_bf16(v1.w)};
                *(u16x8*)&lA[buf][(p * 256 + t) * 8] = ov;
            }
        }
#pragma unroll
        for (int p = 0; p < 2; ++p)
            gl_lds16(TMT + (size_t)(a * NE + jb + srow[p]) * NK + k0 + scol[p],
                     &lB[buf][(p * 256 + t) * 8]);
    };
    stage(0, 0);
    __syncthreads();
    for (int s = 0; s < 32; ++s) {
        int cur = s & 1;
        if (s + 1 < 32) stage(cur ^ 1, s + 1);
        bf16x8 af[4], bfr[4];
#pragma unroll
        for (int i = 0; i < 4; ++i)
            af[i] = *(const bf16x8*)&lA[cur][(wm * 64 + i * 16 + lr) * 32 + ((lc ^ sl) << 3)];
#pragma unroll
        for (int j = 0; j < 4; ++j)
            bfr[j] = *(const bf16x8*)&lB[cur][(wn * 64 + j * 16 + lr) * 32 + ((lc ^ sl) << 3)];
#pragma unroll
        for (int i = 0; i < 4; ++i)
#pragma unroll
            for (int j = 0; j < 4; ++j)
                acc[i][j] = __builtin_amdgcn_mfma_f32_16x16x32_bf16(af[i], bfr[j], acc[i][j], 0, 0, 0);
        __syncthreads();
    }
#pragma unroll
    for (int i = 0; i < 4; ++i) {
#pragma unroll
        for (int r = 0; r < 4; ++r) {
            int bm = m0 + wm * 64 + i * 16 + lc * 4 + r;
            float* orow = attr + ((size_t)bm * NA + a) * NE + jb;
#pragma unroll
            for (int j = 0; j < 4; ++j)
                orow[wn * 64 + j * 16 + lr] = acc[i][j][r];
            if (WB) {
                uint16_t* brow = attrb + ((size_t)bm * NA + a) * NE + jb;
#pragma unroll
                for (int j = 0; j < 4; ++j)
                    brow[wn * 64 + j * 16 + lr] = cvt_bf16(acc[i][j][r]);
            }
        }
    }
}

template<bool AB>
__global__ __launch_bounds__(256) void k_ind2(const float* __restrict__ attrf,
                                              const uint16_t* __restrict__ attrb,
                                              const uint16_t* __restrict__ bwdT,
                                              const float* __restrict__ sw,
                                              float* __restrict__ ind) {
    __shared__ alignas(16) uint16_t lA[2][128 * 32];
    __shared__ alignas(16) uint16_t lB[2][128 * 32];
    int o = blockIdx.x;
    int xcd = o & 7, mt = o >> 3;
    int jt = xcd >> 1, ah = xcd & 1;
    int m0 = mt * 128, jb = jt * 128, a0 = ah * 4;
    int t = threadIdx.x, lane = t & 63;
    int w = t >> 6, wm = w >> 1, wn = w & 1;
    int lr = lane & 15, lc = lane >> 4;
    int sl = swz(lr);
    int srow[2], scol[2];
#pragma unroll
    for (int p = 0; p < 2; ++p) {
        int id = p * 256 + t;
        srow[p] = id >> 2;
        scol[p] = ((id & 3) ^ swz(id >> 2)) << 3;
    }
    f32x4 res[4][4] = {};
    f32x4 acc[4][4] = {};
    auto stage = [&](int buf, int s) {
        int a = a0 + (s >> 4), kk = (s & 15) * 32;
        if (AB) {
#pragma unroll
            for (int p = 0; p < 2; ++p)
                gl_lds16(attrb + ((size_t)(m0 + srow[p]) * NA + a) * NE + kk + scol[p],
                         &lA[buf][(p * 256 + t) * 8]);
        } else {
#pragma unroll
            for (int p = 0; p < 2; ++p) {
                const float* sp = attrf + ((size_t)(m0 + srow[p]) * NA + a) * NE + kk + scol[p];
                float4 v0 = ((const float4*)sp)[0];
                float4 v1 = ((const float4*)sp)[1];
                u16x8 ov = {cvt_bf16(v0.x), cvt_bf16(v0.y), cvt_bf16(v0.z), cvt_bf16(v0.w),
                            cvt_bf16(v1.x), cvt_bf16(v1.y), cvt_bf16(v1.z), cvt_bf16(v1.w)};
                *(u16x8*)&lA[buf][(p * 256 + t) * 8] = ov;
            }
        }
#pragma unroll
        for (int p = 0; p < 2; ++p)
            gl_lds16(bwdT + (size_t)(a * NE + jb + srow[p]) * NE + kk + scol[p],
                     &lB[buf][(p * 256 + t) * 8]);
    };
    stage(0, 0);
    __syncthreads();
    for (int s = 0; s < 64; ++s) {
        int cur = s & 1;
        if (s + 1 < 64) stage(cur ^ 1, s + 1);
        bf16x8 af[4], bfr[4];
#pragma unroll
        for (int i = 0; i < 4; ++i)
            af[i] = *(const bf16x8*)&lA[cur][(wm * 64 + i * 16 + lr) * 32 + ((lc ^ sl) << 3)];
#pragma unroll
        for (int j = 0; j < 4; ++j)
            bfr[j] = *(const bf16x8*)&lB[cur][(wn * 64 + j * 16 + lr) * 32 + ((lc ^ sl) << 3)];
#pragma unroll
        for (int i = 0; i < 4; ++i)
#pragma unroll
            for (int j = 0; j < 4; ++j)
                acc[i][j] = __builtin_amdgcn_mfma_f32_16x16x32_bf16(af[i], bfr[j], acc[i][j], 0, 0, 0);
        if ((s & 15) == 15) {
            float wa = sw[a0 + (s >> 4)];
#pragma unroll
            for (int i = 0; i < 4; ++i)
#pragma unroll
                for (int j = 0; j < 4; ++j) {
#pragma unroll
                    for (int r = 0; r < 4; ++r)
                        res[i][j][r] += wa * fmaxf(acc[i][j][r], 0.f);
                    acc[i][j] = (f32x4){0.f, 0.f, 0.f, 0.f};
                }
        }
        __syncthreads();
    }
#pragma unroll
    for (int i = 0; i < 4; ++i) {
#pragma unroll
        for (int r = 0; r < 4; ++r) {
            int bm = m0 + wm * 64 + i * 16 + lc * 4 + r;
            float* orow = ind + (size_t)bm * NE + jb;
#pragma unroll
            for (int j = 0; j < 4; ++j)
                atomicAdd(&orow[wn * 64 + j * 16 + lr], res[i][j][r]);
        }
    }
}

extern "C" void kernel_launch(void* const* d_in, const int* in_sizes, int n_in,
                              void* d_out, int out_size, void* d_ws, size_t ws_size,
                              hipStream_t stream) {
    (void)in_sizes; (void)n_in; (void)out_size;
    const float* img  = (const float*)d_in[0];
    const float* edge = (const float*)d_in[1];
    const float* lw   = (const float*)d_in[2];
    const float* lb   = (const float*)d_in[3];
    const float* fwd  = (const float*)d_in[4];
    const float* bwd  = (const float*)d_in[5];
    const float* sw   = (const float*)d_in[6];
    float* attr = (float*)d_out;
    float* ind  = attr + (size_t)NB * NA * NE;

    char* ws = (char*)d_ws;
    size_t off = 0;
    auto alloc = [&](size_t bytes) { void* p = ws + off; off += bytes; return p; };
    uint16_t* lwT  = (uint16_t*)alloc((size_t)NK * NE * 2);       // 1 MB
    uint16_t* fwdT = (uint16_t*)alloc((size_t)NA * NE * NE * 2);  // 4 MB
    uint16_t* bwdT = (uint16_t*)alloc((size_t)NA * NE * NE * 2);  // 4 MB
    uint16_t* TMT  = (uint16_t*)alloc((size_t)NN * NK * 2);       // 8 MB
    uint16_t* imgb = (uint16_t*)alloc((size_t)NB * NE * 2);       // 16 MB
    float*    bvec = (float*)alloc((size_t)NN * 4);               // 16 KB

    const size_t BIGB = (size_t)NB * NA * NE * 2;  // 128 MB each
    bool has_attrb = ws_size >= off + BIGB;
    uint16_t* attrb = has_attrb ? (uint16_t*)alloc(BIGB) : (uint16_t*)0;
    bool has_edgeb = ws_size >= off + BIGB;
    uint16_t* edgeb = has_edgeb ? (uint16_t*)alloc(BIGB) : (uint16_t*)0;

    hipMemsetAsync(bvec, 0, (size_t)NN * 4, stream);
    hipMemsetAsync(ind, 0, (size_t)NB * NE * 4, stream);
    k_tcvt<<<dim3(NK / 32, NE / 32, 1), 256, 0, stream>>>(lw, lwT, NE, NK);
    k_tcvt<<<dim3(NE / 32, NE / 32, NA), 256, 0, stream>>>(fwd, fwdT, NE, NE);
    k_tcvt<<<dim3(NE / 32, NE / 32, NA), 256, 0, stream>>>(bwd, bwdT, NE, NE);
    k_cvt4<<<NB * NE / 4 / 256, 256, 0, stream>>>(img, imgb, NB * NE / 4);
    if (has_edgeb)
        k_cvt4<<<NB * NA * NE / 4 / 256, 256, 0, stream>>>(edge, edgeb, NB * NA * NE / 4);
    k_bvec<<<128, 256, 0, stream>>>(lb, fwd, bvec);
    k_prep<<<(NK / 128) * (NN / 128), 256, 0, stream>>>(lwT, fwdT, TMT);

    int mm_grid = (NB / 128) * (NN / 128);
    int ind_grid = (NB / 128) * (NE / 128) * 2;  // a-split 2

    if (has_edgeb && has_attrb) {
        k_mm2<<<mm_grid, 256, 0, stream>>>(imgb, edgeb, TMT, bvec, attr, attrb);
        k_ind3<<<ind_grid, 256, 0, stream>>>(attrb, bwdT, sw, ind);
    } else {
        if (has_edgeb)
            k_mm<true, false><<<mm_grid, 256, 0, stream>>>(imgb, edge, edgeb, TMT, bvec, attr, attrb);
        else if (has_attrb)
            k_mm<false, true><<<mm_grid, 256, 0, stream>>>(imgb, edge, edgeb, TMT, bvec, attr, attrb);
        else
            k_mm<false, false><<<mm_grid, 256, 0, stream>>>(imgb, edge, edgeb, TMT, bvec, attr, attrb);
        if (has_attrb)
            k_ind2<true><<<ind_grid, 256, 0, stream>>>(attr, attrb, bwdT, sw, ind);
        else
            k_ind2<false><<<ind_grid, 256, 0, stream>>>(attr, attrb, bwdT, sw, ind);
    }
}

// Round 6
// 491.498 us; speedup vs baseline: 1.2995x; 1.2995x over previous
//
#include <hip/hip_runtime.h>
#include <cstdint>
#include <cstddef>

#define NB 16384
#define NA 8
#define NE 512
#define NK 1024   // 2E
#define NN 4096   // A*E

typedef __bf16 bf16x8 __attribute__((ext_vector_type(8)));
typedef float  f32x4  __attribute__((ext_vector_type(4)));
typedef uint16_t u16x8 __attribute__((ext_vector_type(8)));

__device__ __forceinline__ uint16_t cvt_bf16(float f) {
    uint32_t u = __builtin_bit_cast(uint32_t, f);
    u += 0x7fffu + ((u >> 16) & 1u);
    return (uint16_t)(u >> 16);
}

// legacy BK=32 chunk swizzle (k_prep only)
__device__ __forceinline__ int swz(int row) { return (row ^ (row >> 2)) & 3; }

// conflict-free BK=32 tile position (16B units): row-pair interleave + 3-bit XOR
// proven 0-conflict in R5 PMC
__device__ __forceinline__ int cf_pos(int row, int c) {
    return ((row >> 1) << 3) + ((((row & 1) << 2) + c) ^ ((row >> 1) & 7));
}

__device__ __forceinline__ void gl_lds16(const void* g, void* l) {
    __builtin_amdgcn_global_load_lds(
        (__attribute__((address_space(1))) void*)(void*)g,
        (__attribute__((address_space(3))) void*)l, 16, 0, 0);
}

// f32 [nmat][R][C] -> bf16 [nmat][C][R]
__global__ __launch_bounds__(256) void k_tcvt(const float* __restrict__ in,
                                              uint16_t* __restrict__ out,
                                              int R, int C) {
    __shared__ float tile[32][33];
    int mat = blockIdx.z;
    int c0 = blockIdx.x * 32, r0 = blockIdx.y * 32;
    int tx = threadIdx.x & 31, ty = threadIdx.x >> 5;
    const float* src = in + (size_t)mat * R * C;
    uint16_t* dst = out + (size_t)mat * R * C;
#pragma unroll
    for (int yy = 0; yy < 4; ++yy) {
        int r = ty + yy * 8;
        tile[r][tx] = src[(size_t)(r0 + r) * C + c0 + tx];
    }
    __syncthreads();
#pragma unroll
    for (int yy = 0; yy < 4; ++yy) {
        int c = ty + yy * 8;
        dst[(size_t)(c0 + c) * R + r0 + tx] = cvt_bf16(tile[tx][c]);
    }
}

// f32 -> bf16 flat, 4 elems/thread
__global__ __launch_bounds__(256) void k_cvt4(const float* __restrict__ in,
                                              uint16_t* __restrict__ out, int n4) {
    int i = blockIdx.x * 256 + threadIdx.x;
    if (i >= n4) return;
    float4 v = ((const float4*)in)[i];
    ushort4 o;
    o.x = cvt_bf16(v.x); o.y = cvt_bf16(v.y); o.z = cvt_bf16(v.z); o.w = cvt_bf16(v.w);
    ((ushort4*)out)[i] = o;
}

// bvec[a*E+j] += partial over 32 i's; 128 blocks, atomics (bvec pre-zeroed)
__global__ __launch_bounds__(256) void k_bvec(const float* __restrict__ lb,
                                              const float* __restrict__ fwd,
                                              float* __restrict__ bvec) {
    int a = blockIdx.x >> 4, i0 = (blockIdx.x & 15) * 32;
    int t = threadIdx.x;
    float s0 = 0.f, s1 = 0.f;
#pragma unroll 4
    for (int i = 0; i < 32; ++i) {
        float w = lb[i0 + i];
        const float* f = fwd + ((size_t)a * NE + i0 + i) * NE;
        s0 = fmaf(w, f[t], s0);
        s1 = fmaf(w, f[t + 256], s1);
    }
    atomicAdd(&bvec[a * NE + t], s0);
    atomicAdd(&bvec[a * NE + t + 256], s1);
}

// TM[m=k'(1024)][n=(a,j)(4096)] = sum_i lwT[m][i]*fwdT[n][i]; store TMT[n][m] bf16
__global__ __launch_bounds__(256) void k_prep(const uint16_t* __restrict__ lwT,
                                              const uint16_t* __restrict__ fwdT,
                                              uint16_t* __restrict__ TMT) {
    __shared__ alignas(16) uint16_t lA[128 * 32];
    __shared__ alignas(16) uint16_t lB[128 * 32];
    int bz = blockIdx.x;
    int nt = bz & 31, mt = bz >> 5;
    int m0 = mt * 128, n0 = nt * 128;
    int t = threadIdx.x, lane = t & 63;
    int w = t >> 6, wm = w >> 1, wn = w & 1;
    int lr = lane & 15, lc = lane >> 4;
    int sl = swz(lr);
    f32x4 acc[4][4] = {};
    for (int k0 = 0; k0 < NE; k0 += 32) {
        __syncthreads();
#pragma unroll
        for (int p = 0; p < 2; ++p) {
            int idx = p * 256 + t;
            int row = idx >> 2, c16 = (idx & 3) ^ swz(row);
            gl_lds16(lwT + (size_t)(m0 + row) * NE + k0 + c16 * 8, lA + idx * 8);
            gl_lds16(fwdT + (size_t)(n0 + row) * NE + k0 + c16 * 8, lB + idx * 8);
        }
        __syncthreads();
        bf16x8 af[4], bfr[4];
#pragma unroll
        for (int i = 0; i < 4; ++i)
            af[i] = *(const bf16x8*)&lA[(wm * 64 + i * 16 + lr) * 32 + ((lc ^ sl) << 3)];
#pragma unroll
        for (int j = 0; j < 4; ++j)
            bfr[j] = *(const bf16x8*)&lB[(wn * 64 + j * 16 + lr) * 32 + ((lc ^ sl) << 3)];
#pragma unroll
        for (int i = 0; i < 4; ++i)
#pragma unroll
            for (int j = 0; j < 4; ++j)
                acc[i][j] = __builtin_amdgcn_mfma_f32_16x16x32_bf16(af[i], bfr[j], acc[i][j], 0, 0, 0);
    }
#pragma unroll
    for (int i = 0; i < 4; ++i) {
        int mb = m0 + wm * 64 + i * 16 + lc * 4;
#pragma unroll
        for (int j = 0; j < 4; ++j) {
            int n = n0 + wn * 64 + j * 16 + lr;
            ushort4 v;
            v.x = cvt_bf16(acc[i][j][0]);
            v.y = cvt_bf16(acc[i][j][1]);
            v.z = cvt_bf16(acc[i][j][2]);
            v.w = cvt_bf16(acc[i][j][3]);
            *(ushort4*)&TMT[(size_t)n * NK + mb] = v;
        }
    }
}

// attr[b,a,j] = img[b]@TM_a[0:512] + edge[b,a]@TM_a[512:1024] + bvec_a[j]
// XCD map (a = xcd), dbuf BK=32, cf_pos layout, __syncthreads schedule,
// edge f32 fused in via T14 async-split (load-early / cvt+ds_write-late).
template<bool WB>
__global__ __launch_bounds__(256) void k_mm3(const uint16_t* __restrict__ imgb,
                                             const float* __restrict__ edge,
                                             const uint16_t* __restrict__ TMT,
                                             const float* __restrict__ bvec,
                                             float* __restrict__ attr,
                                             uint16_t* __restrict__ attrb) {
    __shared__ alignas(16) uint16_t lA[2][128 * 32];
    __shared__ alignas(16) uint16_t lB[2][128 * 32];
    int o = blockIdx.x;            // 4096 = 8 xcd * (4 jt * 128 mt)
    int a = o & 7, idx = o >> 3;
    int jt = idx & 3, mt = idx >> 2;
    int m0 = mt * 128, jb = jt * 128;
    int t = threadIdx.x, lane = t & 63;
    int w = t >> 6, wm = w >> 1, wn = w & 1;
    int lr = lane & 15, lc = lane >> 4;
    // gl_lds source map = inverse of cf_pos: LDS 16B-unit u -> (row, elem-col)
    int srow[2], sc8[2];
#pragma unroll
    for (int p = 0; p < 2; ++p) {
        int u = p * 256 + t;
        int rp = u >> 3, q = (u & 7) ^ (rp & 7);
        srow[p] = (rp << 1) | (q >> 2);
        sc8[p] = (q & 3) << 3;
    }
    // ds_write map for edge path: thread owns (row, c) natural, writes swizzled
    int erow[2], ec[2], epos[2];
#pragma unroll
    for (int p = 0; p < 2; ++p) {
        int u = p * 256 + t;
        erow[p] = u >> 2; ec[p] = u & 3;
        epos[p] = cf_pos(erow[p], ec[p]) * 8;
    }
    int aoff[4], boff[4];
#pragma unroll
    for (int i = 0; i < 4; ++i) {
        aoff[i] = cf_pos(wm * 64 + i * 16 + lr, lc) * 8;
        boff[i] = cf_pos(wn * 64 + i * 16 + lr, lc) * 8;
    }
    auto stage_img = [&](int buf, int s) {
        int k0 = s * 32;
#pragma unroll
        for (int p = 0; p < 2; ++p)
            gl_lds16(imgb + (size_t)(m0 + srow[p]) * NE + k0 + sc8[p],
                     &lA[buf][(p * 256 + t) * 8]);
    };
    auto stage_tmt = [&](int buf, int s) {
        int k0 = s * 32;
#pragma unroll
        for (int p = 0; p < 2; ++p)
            gl_lds16(TMT + (size_t)(a * NE + jb + srow[p]) * NK + k0 + sc8[p],
                     &lB[buf][(p * 256 + t) * 8]);
    };
    f32x4 acc[4][4] = {};
    stage_img(0, 0);
    stage_tmt(0, 0);
    for (int s = 0; s < 32; ++s) {
        int cur = s & 1, nb = cur ^ 1;
        __syncthreads();
        float4 er[2][2];
        bool edgeNext = (s < 31) && (s + 1 >= 16);
        if (s < 31) {
            if (s + 1 < 16) {
                stage_img(nb, s + 1);
            } else {
                int kk = (s + 1 - 16) * 32;
#pragma unroll
                for (int p = 0; p < 2; ++p) {
                    const float* sp = edge + ((size_t)(m0 + erow[p]) * NA + a) * NE + kk + ec[p] * 8;
                    er[p][0] = ((const float4*)sp)[0];
                    er[p][1] = ((const float4*)sp)[1];
                }
            }
            stage_tmt(nb, s + 1);
        }
        bf16x8 af[4], bfr[4];
#pragma unroll
        for (int i = 0; i < 4; ++i) af[i] = *(const bf16x8*)&lA[cur][aoff[i]];
#pragma unroll
        for (int j = 0; j < 4; ++j) bfr[j] = *(const bf16x8*)&lB[cur][boff[j]];
#pragma unroll
        for (int i = 0; i < 4; ++i)
#pragma unroll
            for (int j = 0; j < 4; ++j)
                acc[i][j] = __builtin_amdgcn_mfma_f32_16x16x32_bf16(af[i], bfr[j], acc[i][j], 0, 0, 0);
        if (edgeNext) {
#pragma unroll
            for (int p = 0; p < 2; ++p) {
                u16x8 ov = {cvt_bf16(er[p][0].x), cvt_bf16(er[p][0].y),
                            cvt_bf16(er[p][0].z), cvt_bf16(er[p][0].w),
                            cvt_bf16(er[p][1].x), cvt_bf16(er[p][1].y),
                            cvt_bf16(er[p][1].z), cvt_bf16(er[p][1].w)};
                *(u16x8*)&lA[nb][epos[p]] = ov;
            }
        }
    }
#pragma unroll
    for (int j = 0; j < 4; ++j) {
        float bv = bvec[a * NE + jb + wn * 64 + j * 16 + lr];
#pragma unroll
        for (int i = 0; i < 4; ++i)
#pragma unroll
            for (int r = 0; r < 4; ++r)
                acc[i][j][r] += bv;
    }
#pragma unroll
    for (int i = 0; i < 4; ++i) {
#pragma unroll
        for (int r = 0; r < 4; ++r) {
            int bm = m0 + wm * 64 + i * 16 + lc * 4 + r;
            float* orow = attr + ((size_t)bm * NA + a) * NE + jb;
#pragma unroll
            for (int j = 0; j < 4; ++j)
                orow[wn * 64 + j * 16 + lr] = acc[i][j][r];
            if (WB) {
                uint16_t* brow = attrb + ((size_t)bm * NA + a) * NE + jb;
#pragma unroll
                for (int j = 0; j < 4; ++j)
                    brow[wn * 64 + j * 16 + lr] = cvt_bf16(acc[i][j][r]);
            }
        }
    }
}

// ind[b,j] += sum_{a in half} sw[a]*relu(attr[b,a,:]@bwd_a[:,j])
// XCD map ((jt,ah)=xcd), a-split-2 atomics, dbuf BK=32, cf_pos, syncthreads.
template<bool AB>
__global__ __launch_bounds__(256) void k_ind4(const float* __restrict__ attrf,
                                              const uint16_t* __restrict__ attrb,
                                              const uint16_t* __restrict__ bwdT,
                                              const float* __restrict__ sw,
                                              float* __restrict__ ind) {
    __shared__ alignas(16) uint16_t lA[2][128 * 32];
    __shared__ alignas(16) uint16_t lB[2][128 * 32];
    int o = blockIdx.x;            // 1024 = 8 xcd * 128 mt
    int xcd = o & 7, mt = o >> 3;
    int jt = xcd >> 1, ah = xcd & 1;
    int m0 = mt * 128, jb = jt * 128, a0 = ah * 4;
    int t = threadIdx.x, lane = t & 63;
    int w = t >> 6, wm = w >> 1, wn = w & 1;
    int lr = lane & 15, lc = lane >> 4;
    int srow[2], sc8[2];
#pragma unroll
    for (int p = 0; p < 2; ++p) {
        int u = p * 256 + t;
        int rp = u >> 3, q = (u & 7) ^ (rp & 7);
        srow[p] = (rp << 1) | (q >> 2);
        sc8[p] = (q & 3) << 3;
    }
    int erow[2], ec[2], epos[2];
#pragma unroll
    for (int p = 0; p < 2; ++p) {
        int u = p * 256 + t;
        erow[p] = u >> 2; ec[p] = u & 3;
        epos[p] = cf_pos(erow[p], ec[p]) * 8;
    }
    int aoff[4], boff[4];
#pragma unroll
    for (int i = 0; i < 4; ++i) {
        aoff[i] = cf_pos(wm * 64 + i * 16 + lr, lc) * 8;
        boff[i] = cf_pos(wn * 64 + i * 16 + lr, lc) * 8;
    }
    auto stage = [&](int buf, int s) {
        int aa = a0 + (s >> 4), kk = (s & 15) * 32;
        if (AB) {
#pragma unroll
            for (int p = 0; p < 2; ++p)
                gl_lds16(attrb + ((size_t)(m0 + srow[p]) * NA + aa) * NE + kk + sc8[p],
                         &lA[buf][(p * 256 + t) * 8]);
        } else {
#pragma unroll
            for (int p = 0; p < 2; ++p) {
                const float* sp = attrf + ((size_t)(m0 + erow[p]) * NA + aa) * NE + kk + ec[p] * 8;
                float4 v0 = ((const float4*)sp)[0];
                float4 v1 = ((const float4*)sp)[1];
                u16x8 ov = {cvt_bf16(v0.x), cvt_bf16(v0.y), cvt_bf16(v0.z), cvt_bf16(v0.w),
                            cvt_bf16(v1.x), cvt_bf16(v1.y), cvt_bf16(v1.z), cvt_bf16(v1.w)};
                *(u16x8*)&lA[buf][epos[p]] = ov;
            }
        }
#pragma unroll
        for (int p = 0; p < 2; ++p)
            gl_lds16(bwdT + (size_t)(aa * NE + jb + srow[p]) * NE + kk + sc8[p],
                     &lB[buf][(p * 256 + t) * 8]);
    };
    f32x4 res[4][4] = {};
    f32x4 acc[4][4] = {};
    stage(0, 0);
    for (int s = 0; s < 64; ++s) {
        int cur = s & 1;
        __syncthreads();
        if (s < 63) stage(cur ^ 1, s + 1);
        bf16x8 af[4], bfr[4];
#pragma unroll
        for (int i = 0; i < 4; ++i) af[i] = *(const bf16x8*)&lA[cur][aoff[i]];
#pragma unroll
        for (int j = 0; j < 4; ++j) bfr[j] = *(const bf16x8*)&lB[cur][boff[j]];
#pragma unroll
        for (int i = 0; i < 4; ++i)
#pragma unroll
            for (int j = 0; j < 4; ++j)
                acc[i][j] = __builtin_amdgcn_mfma_f32_16x16x32_bf16(af[i], bfr[j], acc[i][j], 0, 0, 0);
        if ((s & 15) == 15) {
            float wa = sw[a0 + (s >> 4)];
#pragma unroll
            for (int i = 0; i < 4; ++i)
#pragma unroll
                for (int j = 0; j < 4; ++j) {
#pragma unroll
                    for (int r = 0; r < 4; ++r)
                        res[i][j][r] += wa * fmaxf(acc[i][j][r], 0.f);
                    acc[i][j] = (f32x4){0.f, 0.f, 0.f, 0.f};
                }
        }
    }
#pragma unroll
    for (int i = 0; i < 4; ++i) {
#pragma unroll
        for (int r = 0; r < 4; ++r) {
            int bm = m0 + wm * 64 + i * 16 + lc * 4 + r;
            float* orow = ind + (size_t)bm * NE + jb;
#pragma unroll
            for (int j = 0; j < 4; ++j)
                atomicAdd(&orow[wn * 64 + j * 16 + lr], res[i][j][r]);
        }
    }
}

extern "C" void kernel_launch(void* const* d_in, const int* in_sizes, int n_in,
                              void* d_out, int out_size, void* d_ws, size_t ws_size,
                              hipStream_t stream) {
    (void)in_sizes; (void)n_in; (void)out_size;
    const float* img  = (const float*)d_in[0];
    const float* edge = (const float*)d_in[1];
    const float* lw   = (const float*)d_in[2];
    const float* lb   = (const float*)d_in[3];
    const float* fwd  = (const float*)d_in[4];
    const float* bwd  = (const float*)d_in[5];
    const float* sw   = (const float*)d_in[6];
    float* attr = (float*)d_out;
    float* ind  = attr + (size_t)NB * NA * NE;

    char* ws = (char*)d_ws;
    size_t off = 0;
    auto alloc = [&](size_t bytes) { void* p = ws + off; off += bytes; return p; };
    uint16_t* lwT  = (uint16_t*)alloc((size_t)NK * NE * 2);       // 1 MB
    uint16_t* fwdT = (uint16_t*)alloc((size_t)NA * NE * NE * 2);  // 4 MB
    uint16_t* bwdT = (uint16_t*)alloc((size_t)NA * NE * NE * 2);  // 4 MB
    uint16_t* TMT  = (uint16_t*)alloc((size_t)NN * NK * 2);       // 8 MB
    uint16_t* imgb = (uint16_t*)alloc((size_t)NB * NE * 2);       // 16 MB
    float*    bvec = (float*)alloc((size_t)NN * 4);               // 16 KB

    const size_t BIGB = (size_t)NB * NA * NE * 2;  // 128 MB
    bool has_attrb = ws_size >= off + BIGB;
    uint16_t* attrb = has_attrb ? (uint16_t*)alloc(BIGB) : (uint16_t*)0;

    hipMemsetAsync(bvec, 0, (size_t)NN * 4, stream);
    hipMemsetAsync(ind, 0, (size_t)NB * NE * 4, stream);
    k_tcvt<<<dim3(NK / 32, NE / 32, 1), 256, 0, stream>>>(lw, lwT, NE, NK);
    k_tcvt<<<dim3(NE / 32, NE / 32, NA), 256, 0, stream>>>(fwd, fwdT, NE, NE);
    k_tcvt<<<dim3(NE / 32, NE / 32, NA), 256, 0, stream>>>(bwd, bwdT, NE, NE);
    k_cvt4<<<NB * NE / 4 / 256, 256, 0, stream>>>(img, imgb, NB * NE / 4);
    k_bvec<<<128, 256, 0, stream>>>(lb, fwd, bvec);
    k_prep<<<(NK / 128) * (NN / 128), 256, 0, stream>>>(lwT, fwdT, TMT);

    int mm_grid = (NB / 128) * (NN / 128);   // 4096
    int ind_grid = (NB / 128) * (NE / 128) * 2;  // 1024, a-split 2

    if (has_attrb) {
        k_mm3<true><<<mm_grid, 256, 0, stream>>>(imgb, edge, TMT, bvec, attr, attrb);
        k_ind4<true><<<ind_grid, 256, 0, stream>>>(attr, attrb, bwdT, sw, ind);
    } else {
        k_mm3<false><<<mm_grid, 256, 0, stream>>>(imgb, edge, TMT, bvec, attr, attrb);
        k_ind4<false><<<ind_grid, 256, 0, stream>>>(attr, attrb, bwdT, sw, ind);
    }
}

// Round 7
// 462.368 us; speedup vs baseline: 1.3814x; 1.0630x over previous
//
#include <hip/hip_runtime.h>
#include <cstdint>
#include <cstddef>

#define NB 16384
#define NA 8
#define NE 512
#define NK 1024   // 2E
#define NN 4096   // A*E

typedef __bf16 bf16x8 __attribute__((ext_vector_type(8)));
typedef float  f32x4  __attribute__((ext_vector_type(4)));
typedef uint16_t u16x8 __attribute__((ext_vector_type(8)));

__device__ __forceinline__ uint16_t cvt_bf16(float f) {
    uint32_t u = __builtin_bit_cast(uint32_t, f);
    u += 0x7fffu + ((u >> 16) & 1u);
    return (uint16_t)(u >> 16);
}

// legacy BK=32 chunk swizzle (k_prep only)
__device__ __forceinline__ int swz(int row) { return (row ^ (row >> 2)) & 3; }

// conflict-free BK=32 tile position (16B units): row-pair interleave + 3-bit XOR
// proven 0-conflict in R5/R6 PMC
__device__ __forceinline__ int cf_pos(int row, int c) {
    return ((row >> 1) << 3) + ((((row & 1) << 2) + c) ^ ((row >> 1) & 7));
}

__device__ __forceinline__ void gl_lds16(const void* g, void* l) {
    __builtin_amdgcn_global_load_lds(
        (__attribute__((address_space(1))) void*)(void*)g,
        (__attribute__((address_space(3))) void*)l, 16, 0, 0);
}

// f32 [nmat][R][C] -> bf16 [nmat][C][R]
__global__ __launch_bounds__(256) void k_tcvt(const float* __restrict__ in,
                                              uint16_t* __restrict__ out,
                                              int R, int C) {
    __shared__ float tile[32][33];
    int mat = blockIdx.z;
    int c0 = blockIdx.x * 32, r0 = blockIdx.y * 32;
    int tx = threadIdx.x & 31, ty = threadIdx.x >> 5;
    const float* src = in + (size_t)mat * R * C;
    uint16_t* dst = out + (size_t)mat * R * C;
#pragma unroll
    for (int yy = 0; yy < 4; ++yy) {
        int r = ty + yy * 8;
        tile[r][tx] = src[(size_t)(r0 + r) * C + c0 + tx];
    }
    __syncthreads();
#pragma unroll
    for (int yy = 0; yy < 4; ++yy) {
        int c = ty + yy * 8;
        dst[(size_t)(c0 + c) * R + r0 + tx] = cvt_bf16(tile[tx][c]);
    }
}

// f32 -> bf16 flat, 4 elems/thread
__global__ __launch_bounds__(256) void k_cvt4(const float* __restrict__ in,
                                              uint16_t* __restrict__ out, int n4) {
    int i = blockIdx.x * 256 + threadIdx.x;
    if (i >= n4) return;
    float4 v = ((const float4*)in)[i];
    ushort4 o;
    o.x = cvt_bf16(v.x); o.y = cvt_bf16(v.y); o.z = cvt_bf16(v.z); o.w = cvt_bf16(v.w);
    ((ushort4*)out)[i] = o;
}

// bvec[a*E+j] += partial over 32 i's; 128 blocks, atomics (bvec pre-zeroed)
__global__ __launch_bounds__(256) void k_bvec(const float* __restrict__ lb,
                                              const float* __restrict__ fwd,
                                              float* __restrict__ bvec) {
    int a = blockIdx.x >> 4, i0 = (blockIdx.x & 15) * 32;
    int t = threadIdx.x;
    float s0 = 0.f, s1 = 0.f;
#pragma unroll 4
    for (int i = 0; i < 32; ++i) {
        float w = lb[i0 + i];
        const float* f = fwd + ((size_t)a * NE + i0 + i) * NE;
        s0 = fmaf(w, f[t], s0);
        s1 = fmaf(w, f[t + 256], s1);
    }
    atomicAdd(&bvec[a * NE + t], s0);
    atomicAdd(&bvec[a * NE + t + 256], s1);
}

// TM[m=k'(1024)][n=(a,j)(4096)] = sum_i lwT[m][i]*fwdT[n][i]; store TMT[n][m] bf16
__global__ __launch_bounds__(256) void k_prep(const uint16_t* __restrict__ lwT,
                                              const uint16_t* __restrict__ fwdT,
                                              uint16_t* __restrict__ TMT) {
    __shared__ alignas(16) uint16_t lA[128 * 32];
    __shared__ alignas(16) uint16_t lB[128 * 32];
    int bz = blockIdx.x;
    int nt = bz & 31, mt = bz >> 5;
    int m0 = mt * 128, n0 = nt * 128;
    int t = threadIdx.x, lane = t & 63;
    int w = t >> 6, wm = w >> 1, wn = w & 1;
    int lr = lane & 15, lc = lane >> 4;
    int sl = swz(lr);
    f32x4 acc[4][4] = {};
    for (int k0 = 0; k0 < NE; k0 += 32) {
        __syncthreads();
#pragma unroll
        for (int p = 0; p < 2; ++p) {
            int idx = p * 256 + t;
            int row = idx >> 2, c16 = (idx & 3) ^ swz(row);
            gl_lds16(lwT + (size_t)(m0 + row) * NE + k0 + c16 * 8, lA + idx * 8);
            gl_lds16(fwdT + (size_t)(n0 + row) * NE + k0 + c16 * 8, lB + idx * 8);
        }
        __syncthreads();
        bf16x8 af[4], bfr[4];
#pragma unroll
        for (int i = 0; i < 4; ++i)
            af[i] = *(const bf16x8*)&lA[(wm * 64 + i * 16 + lr) * 32 + ((lc ^ sl) << 3)];
#pragma unroll
        for (int j = 0; j < 4; ++j)
            bfr[j] = *(const bf16x8*)&lB[(wn * 64 + j * 16 + lr) * 32 + ((lc ^ sl) << 3)];
#pragma unroll
        for (int i = 0; i < 4; ++i)
#pragma unroll
            for (int j = 0; j < 4; ++j)
                acc[i][j] = __builtin_amdgcn_mfma_f32_16x16x32_bf16(af[i], bfr[j], acc[i][j], 0, 0, 0);
    }
#pragma unroll
    for (int i = 0; i < 4; ++i) {
        int mb = m0 + wm * 64 + i * 16 + lc * 4;
#pragma unroll
        for (int j = 0; j < 4; ++j) {
            int n = n0 + wn * 64 + j * 16 + lr;
            ushort4 v;
            v.x = cvt_bf16(acc[i][j][0]);
            v.y = cvt_bf16(acc[i][j][1]);
            v.z = cvt_bf16(acc[i][j][2]);
            v.w = cvt_bf16(acc[i][j][3]);
            *(ushort4*)&TMT[(size_t)n * NK + mb] = v;
        }
    }
}

// attr[b,a,j] = img[b]@TM_a[0:512] + edge[b,a]@TM_a[512:1024] + bvec_a[j]
// 512 threads / 8 waves, 128x256 tile, BK=32 dbuf, cf_pos layout, a=XCD,
// fused edge f32 (T14 load-early / cvt+ds_write-late).
template<bool WB>
__global__ __launch_bounds__(512) void k_mm4(const uint16_t* __restrict__ imgb,
                                             const float* __restrict__ edge,
                                             const uint16_t* __restrict__ TMT,
                                             const float* __restrict__ bvec,
                                             float* __restrict__ attr,
                                             uint16_t* __restrict__ attrb) {
    __shared__ alignas(16) uint16_t lA[2][128 * 32];   // 2 x 8 KB
    __shared__ alignas(16) uint16_t lB[2][256 * 32];   // 2 x 16 KB
    int o = blockIdx.x;             // 2048 = 8 xcd * (2 jt * 128 mt)
    int a = o & 7, idx = o >> 3;
    int jt = idx & 1, mt = idx >> 1;
    int m0 = mt * 128, jb = jt * 256;
    int t = threadIdx.x, lane = t & 63;
    int w = t >> 6, wm = w >> 2, wn = w & 3;
    int lr = lane & 15, lc = lane >> 4;
    // A stage map (1 unit/thread): inverse of cf_pos
    int rpA = t >> 3, qA = (t & 7) ^ (rpA & 7);
    int srA = (rpA << 1) | (qA >> 2), scA = (qA & 3) << 3;
    // B stage map (2 units/thread)
    int srB[2], scB[2];
#pragma unroll
    for (int p = 0; p < 2; ++p) {
        int u = t + p * 512;
        int rp = u >> 3, q = (u & 7) ^ (rp & 7);
        srB[p] = (rp << 1) | (q >> 2);
        scB[p] = (q & 3) << 3;
    }
    // edge f32 path: thread owns (row, chunk) natural, writes swizzled
    int er = t >> 2, ec = t & 3;
    int epos = cf_pos(er, ec) * 8;
    int aoff[4], boff[4];
#pragma unroll
    for (int i = 0; i < 4; ++i) {
        aoff[i] = cf_pos(wm * 64 + i * 16 + lr, lc) * 8;
        boff[i] = cf_pos(wn * 64 + i * 16 + lr, lc) * 8;
    }
    auto stage_img = [&](int buf, int s) {
        gl_lds16(imgb + (size_t)(m0 + srA) * NE + s * 32 + scA, &lA[buf][t * 8]);
    };
    auto stage_tmt = [&](int buf, int s) {
#pragma unroll
        for (int p = 0; p < 2; ++p)
            gl_lds16(TMT + (size_t)(a * NE + jb + srB[p]) * NK + s * 32 + scB[p],
                     &lB[buf][(t + p * 512) * 8]);
    };
    f32x4 acc[4][4] = {};
    stage_img(0, 0);
    stage_tmt(0, 0);
    for (int s = 0; s < 32; ++s) {
        int cur = s & 1, nb = cur ^ 1;
        __syncthreads();
        float4 e0, e1;
        bool eN = (s < 31) && (s + 1 >= 16);
        if (s < 31) {
            if (s + 1 < 16) {
                stage_img(nb, s + 1);
            } else {
                int kk = (s + 1 - 16) * 32;
                const float* sp = edge + ((size_t)(m0 + er) * NA + a) * NE + kk + ec * 8;
                e0 = ((const float4*)sp)[0];
                e1 = ((const float4*)sp)[1];
            }
            stage_tmt(nb, s + 1);
        }
        bf16x8 af[4], bfr[4];
#pragma unroll
        for (int i = 0; i < 4; ++i) af[i] = *(const bf16x8*)&lA[cur][aoff[i]];
#pragma unroll
        for (int j = 0; j < 4; ++j) bfr[j] = *(const bf16x8*)&lB[cur][boff[j]];
#pragma unroll
        for (int i = 0; i < 4; ++i)
#pragma unroll
            for (int j = 0; j < 4; ++j)
                acc[i][j] = __builtin_amdgcn_mfma_f32_16x16x32_bf16(af[i], bfr[j], acc[i][j], 0, 0, 0);
        if (eN) {
            u16x8 ov = {cvt_bf16(e0.x), cvt_bf16(e0.y), cvt_bf16(e0.z), cvt_bf16(e0.w),
                        cvt_bf16(e1.x), cvt_bf16(e1.y), cvt_bf16(e1.z), cvt_bf16(e1.w)};
            *(u16x8*)&lA[nb][epos] = ov;
        }
    }
#pragma unroll
    for (int j = 0; j < 4; ++j) {
        float bv = bvec[a * NE + jb + wn * 64 + j * 16 + lr];
#pragma unroll
        for (int i = 0; i < 4; ++i)
#pragma unroll
            for (int r = 0; r < 4; ++r)
                acc[i][j][r] += bv;
    }
#pragma unroll
    for (int i = 0; i < 4; ++i) {
#pragma unroll
        for (int r = 0; r < 4; ++r) {
            int bm = m0 + wm * 64 + i * 16 + lc * 4 + r;
            float* orow = attr + ((size_t)bm * NA + a) * NE + jb;
#pragma unroll
            for (int j = 0; j < 4; ++j)
                orow[wn * 64 + j * 16 + lr] = acc[i][j][r];
            if (WB) {
                uint16_t* brow = attrb + ((size_t)bm * NA + a) * NE + jb;
#pragma unroll
                for (int j = 0; j < 4; ++j)
                    brow[wn * 64 + j * 16 + lr] = cvt_bf16(acc[i][j][r]);
            }
        }
    }
}

// ind[b,j] += sum_{a in half} sw[a]*relu(attr[b,a,:]@bwd_a[:,j])
// XCD map ((jt,ah)=xcd), a-split-2 atomics, dbuf BK=32, cf_pos, syncthreads.
template<bool AB>
__global__ __launch_bounds__(256) void k_ind4(const float* __restrict__ attrf,
                                              const uint16_t* __restrict__ attrb,
                                              const uint16_t* __restrict__ bwdT,
                                              const float* __restrict__ sw,
                                              float* __restrict__ ind) {
    __shared__ alignas(16) uint16_t lA[2][128 * 32];
    __shared__ alignas(16) uint16_t lB[2][128 * 32];
    int o = blockIdx.x;            // 1024 = 8 xcd * 128 mt
    int xcd = o & 7, mt = o >> 3;
    int jt = xcd >> 1, ah = xcd & 1;
    int m0 = mt * 128, jb = jt * 128, a0 = ah * 4;
    int t = threadIdx.x, lane = t & 63;
    int w = t >> 6, wm = w >> 1, wn = w & 1;
    int lr = lane & 15, lc = lane >> 4;
    int srow[2], sc8[2];
#pragma unroll
    for (int p = 0; p < 2; ++p) {
        int u = p * 256 + t;
        int rp = u >> 3, q = (u & 7) ^ (rp & 7);
        srow[p] = (rp << 1) | (q >> 2);
        sc8[p] = (q & 3) << 3;
    }
    int erow[2], ec[2], epos[2];
#pragma unroll
    for (int p = 0; p < 2; ++p) {
        int u = p * 256 + t;
        erow[p] = u >> 2; ec[p] = u & 3;
        epos[p] = cf_pos(erow[p], ec[p]) * 8;
    }
    int aoff[4], boff[4];
#pragma unroll
    for (int i = 0; i < 4; ++i) {
        aoff[i] = cf_pos(wm * 64 + i * 16 + lr, lc) * 8;
        boff[i] = cf_pos(wn * 64 + i * 16 + lr, lc) * 8;
    }
    auto stage = [&](int buf, int s) {
        int aa = a0 + (s >> 4), kk = (s & 15) * 32;
        if (AB) {
#pragma unroll
            for (int p = 0; p < 2; ++p)
                gl_lds16(attrb + ((size_t)(m0 + srow[p]) * NA + aa) * NE + kk + sc8[p],
                         &lA[buf][(p * 256 + t) * 8]);
        } else {
#pragma unroll
            for (int p = 0; p < 2; ++p) {
                const float* sp = attrf + ((size_t)(m0 + erow[p]) * NA + aa) * NE + kk + ec[p] * 8;
                float4 v0 = ((const float4*)sp)[0];
                float4 v1 = ((const float4*)sp)[1];
                u16x8 ov = {cvt_bf16(v0.x), cvt_bf16(v0.y), cvt_bf16(v0.z), cvt_bf16(v0.w),
                            cvt_bf16(v1.x), cvt_bf16(v1.y), cvt_bf16(v1.z), cvt_bf16(v1.w)};
                *(u16x8*)&lA[buf][epos[p]] = ov;
            }
        }
#pragma unroll
        for (int p = 0; p < 2; ++p)
            gl_lds16(bwdT + (size_t)(aa * NE + jb + srow[p]) * NE + kk + sc8[p],
                     &lB[buf][(p * 256 + t) * 8]);
    };
    f32x4 res[4][4] = {};
    f32x4 acc[4][4] = {};
    stage(0, 0);
    for (int s = 0; s < 64; ++s) {
        int cur = s & 1;
        __syncthreads();
        if (s < 63) stage(cur ^ 1, s + 1);
        bf16x8 af[4], bfr[4];
#pragma unroll
        for (int i = 0; i < 4; ++i) af[i] = *(const bf16x8*)&lA[cur][aoff[i]];
#pragma unroll
        for (int j = 0; j < 4; ++j) bfr[j] = *(const bf16x8*)&lB[cur][boff[j]];
#pragma unroll
        for (int i = 0; i < 4; ++i)
#pragma unroll
            for (int j = 0; j < 4; ++j)
                acc[i][j] = __builtin_amdgcn_mfma_f32_16x16x32_bf16(af[i], bfr[j], acc[i][j], 0, 0, 0);
        if ((s & 15) == 15) {
            float wa = sw[a0 + (s >> 4)];
#pragma unroll
            for (int i = 0; i < 4; ++i)
#pragma unroll
                for (int j = 0; j < 4; ++j) {
#pragma unroll
                    for (int r = 0; r < 4; ++r)
                        res[i][j][r] += wa * fmaxf(acc[i][j][r], 0.f);
                    acc[i][j] = (f32x4){0.f, 0.f, 0.f, 0.f};
                }
        }
    }
#pragma unroll
    for (int i = 0; i < 4; ++i) {
#pragma unroll
        for (int r = 0; r < 4; ++r) {
            int bm = m0 + wm * 64 + i * 16 + lc * 4 + r;
            float* orow = ind + (size_t)bm * NE + jb;
#pragma unroll
            for (int j = 0; j < 4; ++j)
                atomicAdd(&orow[wn * 64 + j * 16 + lr], res[i][j][r]);
        }
    }
}

extern "C" void kernel_launch(void* const* d_in, const int* in_sizes, int n_in,
                              void* d_out, int out_size, void* d_ws, size_t ws_size,
                              hipStream_t stream) {
    (void)in_sizes; (void)n_in; (void)out_size;
    const float* img  = (const float*)d_in[0];
    const float* edge = (const float*)d_in[1];
    const float* lw   = (const float*)d_in[2];
    const float* lb   = (const float*)d_in[3];
    const float* fwd  = (const float*)d_in[4];
    const float* bwd  = (const float*)d_in[5];
    const float* sw   = (const float*)d_in[6];
    float* attr = (float*)d_out;
    float* ind  = attr + (size_t)NB * NA * NE;

    char* ws = (char*)d_ws;
    size_t off = 0;
    auto alloc = [&](size_t bytes) { void* p = ws + off; off += bytes; return p; };
    uint16_t* lwT  = (uint16_t*)alloc((size_t)NK * NE * 2);       // 1 MB
    uint16_t* fwdT = (uint16_t*)alloc((size_t)NA * NE * NE * 2);  // 4 MB
    uint16_t* bwdT = (uint16_t*)alloc((size_t)NA * NE * NE * 2);  // 4 MB
    uint16_t* TMT  = (uint16_t*)alloc((size_t)NN * NK * 2);       // 8 MB
    uint16_t* imgb = (uint16_t*)alloc((size_t)NB * NE * 2);       // 16 MB
    float*    bvec = (float*)alloc((size_t)NN * 4);               // 16 KB

    const size_t BIGB = (size_t)NB * NA * NE * 2;  // 128 MB
    bool has_attrb = ws_size >= off + BIGB;
    uint16_t* attrb = has_attrb ? (uint16_t*)alloc(BIGB) : (uint16_t*)0;

    hipMemsetAsync(bvec, 0, (size_t)NN * 4, stream);
    hipMemsetAsync(ind, 0, (size_t)NB * NE * 4, stream);
    k_tcvt<<<dim3(NK / 32, NE / 32, 1), 256, 0, stream>>>(lw, lwT, NE, NK);
    k_tcvt<<<dim3(NE / 32, NE / 32, NA), 256, 0, stream>>>(fwd, fwdT, NE, NE);
    k_tcvt<<<dim3(NE / 32, NE / 32, NA), 256, 0, stream>>>(bwd, bwdT, NE, NE);
    k_cvt4<<<NB * NE / 4 / 256, 256, 0, stream>>>(img, imgb, NB * NE / 4);
    k_bvec<<<128, 256, 0, stream>>>(lb, fwd, bvec);
    k_prep<<<(NK / 128) * (NN / 128), 256, 0, stream>>>(lwT, fwdT, TMT);

    int mm_grid = 8 * 2 * (NB / 128);        // 2048 blocks of 512 threads
    int ind_grid = (NB / 128) * (NE / 128) * 2;  // 1024, a-split 2

    if (has_attrb) {
        k_mm4<true><<<mm_grid, 512, 0, stream>>>(imgb, edge, TMT, bvec, attr, attrb);
        k_ind4<true><<<ind_grid, 256, 0, stream>>>(attr, attrb, bwdT, sw, ind);
    } else {
        k_mm4<false><<<mm_grid, 512, 0, stream>>>(imgb, edge, TMT, bvec, attr, attrb);
        k_ind4<false><<<ind_grid, 256, 0, stream>>>(attr, attrb, bwdT, sw, ind);
    }
}